// Round 4
// baseline (2014.245 us; speedup 1.0000x reference)
//
#include <hip/hip_runtime.h>

typedef unsigned short u16;
typedef unsigned int   u32;
typedef _Float16       f16;

#define B_SZ 2048
#define S_SZ 1024
#define N3   3072
#define F_SZ 50

typedef f16    f16x8  __attribute__((ext_vector_type(8)));
typedef float  f32x4  __attribute__((ext_vector_type(4)));
typedef u32    u32x4  __attribute__((ext_vector_type(4)));

// ---------------------------------------------------------------------------
// Mx[2][3072] = W_emb @ W_gru[0:1024, :]   (fp32, exact path for the x-part)
__global__ __launch_bounds__(256) void make_mx(
    const float* __restrict__ We, const float* __restrict__ Wg,
    float* __restrict__ Mx)
{
    int j = blockIdx.x * 256 + threadIdx.x;
    float s0 = 0.f, s1 = 0.f;
    #pragma unroll 4
    for (int k = 0; k < S_SZ; k++) {
        float w = Wg[(size_t)k * N3 + j];
        s0 += We[k] * w;
        s1 += We[S_SZ + k] * w;
    }
    Mx[j] = s0;
    Mx[N3 + j] = s1;
}

// ---------------------------------------------------------------------------
// Wt[n][k] = fp16(W_gru[1024+k][n])
__global__ __launch_bounds__(256) void transpose_w(
    const float* __restrict__ Wg, f16* __restrict__ Wt)
{
    __shared__ float tile[32][33];
    int n0 = blockIdx.x * 32, k0 = blockIdx.y * 32;
    int c = threadIdx.x & 31, r = threadIdx.x >> 5;
    #pragma unroll
    for (int s = 0; s < 4; s++) {
        int rr = r + s * 8;
        tile[rr][c] = Wg[(size_t)(S_SZ + k0 + rr) * N3 + n0 + c];
    }
    __syncthreads();
    #pragma unroll
    for (int s = 0; s < 4; s++) {
        int rr = r + s * 8;
        Wt[(size_t)(n0 + rr) * S_SZ + k0 + c] = (f16)tile[c][rr];
    }
}

// ---------------------------------------------------------------------------
// parts[m-m_base][n] = sum_k hh[m][k]*Wt[n][k] + act[m][t][:] . Mx[:][n]
__global__ __launch_bounds__(256) void gemm_step(
    const f16* __restrict__ Wt,    // [3072][1024] fp16
    const f16* __restrict__ hh,    // [2048][1024] fp16 shadow state (ws)
    const float* __restrict__ Mx,  // [2][3072]
    const float* __restrict__ act, // [2048][50][2]
    f16* __restrict__ parts,       // [rows][3072] f16
    int t, int m_base)
{
    __shared__ __align__(16) f16 As[128 * 72];
    __shared__ __align__(16) f16 Bs[128 * 72];
    const int m0 = m_base + blockIdx.x * 128;
    const int n0 = blockIdx.y * 128;
    const int tid = threadIdx.x;
    const int lane = tid & 63;
    const int wave = tid >> 6;
    const int wr = (wave >> 1) * 64;
    const int wc = (wave & 1) * 64;
    const int quad = lane >> 4, lrow = lane & 15;

    f32x4 acc[4][4];
    #pragma unroll
    for (int i = 0; i < 4; i++)
        #pragma unroll
        for (int j = 0; j < 4; j++)
            acc[i][j] = (f32x4){0.f, 0.f, 0.f, 0.f};

    for (int kb = 0; kb < S_SZ; kb += 64) {
        __syncthreads();
        #pragma unroll
        for (int c = 0; c < 4; c++) {
            int idx = tid + c * 256;
            int row = idx >> 3, kc = (idx & 7) * 8;
            *(u32x4*)&As[row * 72 + kc] =
                *(const u32x4*)&hh[(size_t)(m0 + row) * S_SZ + kb + kc];
            *(u32x4*)&Bs[row * 72 + kc] =
                *(const u32x4*)&Wt[(size_t)(n0 + row) * S_SZ + kb + kc];
        }
        __syncthreads();
        #pragma unroll
        for (int kk = 0; kk < 64; kk += 32) {
            f16x8 a[4], b[4];
            #pragma unroll
            for (int i = 0; i < 4; i++)
                a[i] = __builtin_bit_cast(f16x8,
                    *(const u32x4*)&As[(wr + i * 16 + lrow) * 72 + kk + quad * 8]);
            #pragma unroll
            for (int j = 0; j < 4; j++)
                b[j] = __builtin_bit_cast(f16x8,
                    *(const u32x4*)&Bs[(wc + j * 16 + lrow) * 72 + kk + quad * 8]);
            #pragma unroll
            for (int i = 0; i < 4; i++)
                #pragma unroll
                for (int j = 0; j < 4; j++)
                    acc[i][j] = __builtin_amdgcn_mfma_f32_16x16x32_f16(
                        a[i], b[j], acc[i][j], 0, 0, 0);
        }
    }

    #pragma unroll
    for (int i = 0; i < 4; i++) {
        #pragma unroll
        for (int r = 0; r < 4; r++) {
            int m = m0 + wr + i * 16 + quad * 4 + r;
            float a0 = act[((size_t)m * F_SZ + t) * 2 + 0];
            float a1 = act[((size_t)m * F_SZ + t) * 2 + 1];
            #pragma unroll
            for (int j = 0; j < 4; j++) {
                int n = n0 + wc + j * 16 + lrow;
                parts[(size_t)(m - m_base) * N3 + n] =
                    (f16)(acc[i][j][r] + a0 * Mx[n] + a1 * Mx[N3 + n]);
            }
        }
    }
}

// ---------------------------------------------------------------------------
// LayerNorm + gates + h update. One block per row. fp32 state lives in d_out.
__global__ __launch_bounds__(256) void ln_gate_step(
    const f16* __restrict__ parts,
    const float* __restrict__ gamma,
    const float* __restrict__ beta,
    float* __restrict__ h,          // fp32 state == d_out[0 .. B*S)
    f16* __restrict__ hh,           // fp16 shadow (ws) for next GEMM
    int m_base)
{
    const int rloc = blockIdx.x;
    const int row  = m_base + rloc;
    const int tid  = threadIdx.x;
    const f16* p = parts + (size_t)rloc * N3;
    float v[12];
    float s = 0.f, ss = 0.f;
    #pragma unroll
    for (int q = 0; q < 12; q++) {
        float x = (float)p[tid + q * 256];
        v[q] = x; s += x; ss += x * x;
    }
    #pragma unroll
    for (int o = 32; o > 0; o >>= 1) {
        s  += __shfl_down(s, o);
        ss += __shfl_down(ss, o);
    }
    __shared__ float red[8];
    int lane = tid & 63, wave = tid >> 6;
    if (lane == 0) { red[wave] = s; red[4 + wave] = ss; }
    __syncthreads();
    float S  = red[0] + red[1] + red[2] + red[3];
    float SS = red[4] + red[5] + red[6] + red[7];
    float mean = S * (1.f / N3);
    float var  = SS * (1.f / N3) - mean * mean;
    float rstd = rsqrtf(var + 1e-3f);
    #pragma unroll
    for (int q = 0; q < 12; q++) {
        int j = tid + q * 256;
        v[q] = (v[q] - mean) * rstd * gamma[j] + beta[j];
    }
    #pragma unroll
    for (int q = 0; q < 4; q++) {
        int i = tid + q * 256;
        float r = 1.f / (1.f + __expf(-v[q]));
        float c = tanhf(r * v[q + 4]);
        float u = 1.f / (1.f + __expf(-(v[q + 8] - 1.f)));
        size_t idx = (size_t)row * S_SZ + i;
        float hp = h[idx];
        float hn = u * c + (1.f - u) * hp;
        h[idx]  = hn;
        hh[idx] = (f16)hn;
    }
}

// ---------------------------------------------------------------------------
// out[B*S + row*2 + {0,1}] = h_row @ W_dec + b_dec   (fp32)
__global__ __launch_bounds__(256) void final_out(
    const float* __restrict__ h, const float* __restrict__ Wd,
    const float* __restrict__ bd, float* __restrict__ out)
{
    int row = blockIdx.x * 4 + (threadIdx.x >> 6);
    int lane = threadIdx.x & 63;
    const float* hr = h + (size_t)row * S_SZ;
    float s0 = 0.f, s1 = 0.f;
    #pragma unroll
    for (int k = lane; k < S_SZ; k += 64) {
        float x = hr[k];
        s0 += x * Wd[k * 2];
        s1 += x * Wd[k * 2 + 1];
    }
    #pragma unroll
    for (int o = 32; o > 0; o >>= 1) {
        s0 += __shfl_down(s0, o);
        s1 += __shfl_down(s1, o);
    }
    if (lane == 0) {
        out[(size_t)B_SZ * S_SZ + row * 2 + 0] = s0 + bd[0];
        out[(size_t)B_SZ * S_SZ + row * 2 + 1] = s1 + bd[1];
    }
}

// ---------------------------------------------------------------------------
extern "C" void kernel_launch(void* const* d_in, const int* in_sizes, int n_in,
                              void* d_out, int out_size, void* d_ws, size_t ws_size,
                              hipStream_t stream)
{
    const float* act = (const float*)d_in[0]; // [2048][50][2]
    const float* We  = (const float*)d_in[1]; // [2][1024]
    const float* Wg  = (const float*)d_in[2]; // [2048][3072]
    const float* lng = (const float*)d_in[3]; // [3072]
    const float* lnb = (const float*)d_in[4]; // [3072]
    const float* Wd  = (const float*)d_in[5]; // [1024][2]
    const float* bd  = (const float*)d_in[6]; // [2]
    float* out = (float*)d_out;               // fp32 [B*S h_last][B*2 outputs]
    float* h   = out;                         // fp32 h state aliased in d_out

    char* ws = (char*)d_ws;
    f16*   Wt = (f16*)ws;                       // 6,291,456 B
    float* Mx = (float*)(ws + 6291456);         //    24,576 B
    f16*   hh = (f16*)(ws + 6316032);           // 4,194,304 B fp16 shadow state
    const size_t BASE = 6316032 + 4194304;      // 10,510,336
    f16* parts = (f16*)(ws + BASE);
    size_t avail = (ws_size > BASE) ? ws_size - BASE : 0;
    int rows = 2048;
    while (rows > 128 && (size_t)rows * N3 * 2 > avail) rows >>= 1;

    hipMemsetAsync(h, 0, (size_t)B_SZ * S_SZ * 4, stream);   // zero fp32 state
    hipMemsetAsync(hh, 0, (size_t)B_SZ * S_SZ * 2, stream);  // zero fp16 shadow
    make_mx<<<N3 / 256, 256, 0, stream>>>(We, Wg, Mx);
    transpose_w<<<dim3(N3 / 32, S_SZ / 32), 256, 0, stream>>>(Wg, Wt);

    for (int t = 0; t < F_SZ; t++) {
        for (int mb = 0; mb < B_SZ; mb += rows) {
            gemm_step<<<dim3(rows / 128, N3 / 128), 256, 0, stream>>>(
                Wt, hh, Mx, act, parts, t, mb);
            ln_gate_step<<<rows, 256, 0, stream>>>(parts, lng, lnb, h, hh, mb);
        }
    }
    final_out<<<B_SZ / 4, 256, 0, stream>>>(h, Wd, bd, out);
}

// Round 5
// 1511.673 us; speedup vs baseline: 1.3325x; 1.3325x over previous
//
#include <hip/hip_runtime.h>

typedef unsigned short u16;
typedef unsigned int   u32;
typedef _Float16       f16;

#define B_SZ 2048
#define S_SZ 1024
#define N3   3072
#define F_SZ 50

typedef f16    f16x8 __attribute__((ext_vector_type(8)));
typedef f16    f16x4 __attribute__((ext_vector_type(4)));
typedef float  f32x4 __attribute__((ext_vector_type(4)));
typedef u32    u32x4 __attribute__((ext_vector_type(4)));

// async global->LDS, 16B per lane; LDS dest = base + lane*16 (wave-uniform base)
__device__ __forceinline__ void glds16(const void* g, void* l) {
    __builtin_amdgcn_global_load_lds(
        (const __attribute__((address_space(1))) u32*)g,
        (__attribute__((address_space(3))) u32*)l, 16, 0, 0);
}

// ---------------------------------------------------------------------------
// Mx[2][3072] = W_emb @ W_gru[0:1024, :]  (split-K + atomics; Mx pre-zeroed)
__global__ __launch_bounds__(256) void make_mx(
    const float* __restrict__ We, const float* __restrict__ Wg,
    float* __restrict__ Mx)
{
    int j  = blockIdx.x * 256 + threadIdx.x;   // 0..3071
    int k0 = blockIdx.y * 64;                  // 16 k-chunks
    float s0 = 0.f, s1 = 0.f;
    #pragma unroll 4
    for (int k = k0; k < k0 + 64; k++) {
        float w = Wg[(size_t)k * N3 + j];
        s0 += We[k] * w;
        s1 += We[S_SZ + k] * w;
    }
    atomicAdd(&Mx[j], s0);
    atomicAdd(&Mx[N3 + j], s1);
}

// ---------------------------------------------------------------------------
// Wt[n][k] = fp16(W_gru[1024+k][n])
__global__ __launch_bounds__(256) void transpose_w(
    const float* __restrict__ Wg, f16* __restrict__ Wt)
{
    __shared__ float tile[32][33];
    int n0 = blockIdx.x * 32, k0 = blockIdx.y * 32;
    int c = threadIdx.x & 31, r = threadIdx.x >> 5;
    #pragma unroll
    for (int s = 0; s < 4; s++) {
        int rr = r + s * 8;
        tile[rr][c] = Wg[(size_t)(S_SZ + k0 + rr) * N3 + n0 + c];
    }
    __syncthreads();
    #pragma unroll
    for (int s = 0; s < 4; s++) {
        int rr = r + s * 8;
        Wt[(size_t)(n0 + rr) * S_SZ + k0 + c] = (f16)tile[c][rr];
    }
}

// ---------------------------------------------------------------------------
// 64x128 tile, BK=64, glds16 staging, XOR-swizzled unpadded LDS.
// LDS layout: X[row][colh] with stored (row, c) = global (row, c ^ ((row&7)*8)).
__global__ __launch_bounds__(256) void gemm_step(
    const f16* __restrict__ Wt,    // [3072][1024] fp16
    const f16* __restrict__ hh,    // [2048][1024] fp16 shadow state
    const float* __restrict__ Mx,  // [2][3072]
    const float* __restrict__ act, // [2048][50][2]
    f16* __restrict__ parts,       // [rows][3072] f16
    int t, int m_base)
{
    __shared__ __align__(16) f16 As[64 * 64];    // 8 KB
    __shared__ __align__(16) f16 Bs[128 * 64];   // 16 KB
    const int m0 = m_base + blockIdx.x * 64;
    const int n0 = blockIdx.y * 128;
    const int tid  = threadIdx.x;
    const int lane = tid & 63;
    const int wave = tid >> 6;
    const int wr = (wave >> 1) * 32;   // wave row offset (A)
    const int wc = (wave & 1) * 64;    // wave col offset (B)
    const int quad = lane >> 4, lrow = lane & 15;
    const int swz = (lrow & 7) * 8;

    // staging lane geometry: 8 rows x 64 halves per 1KB chunk
    const int lrow8 = lane >> 3;
    const int scolh = ((lane & 7) * 8) ^ (lrow8 * 8);  // swizzled source col

    f32x4 acc[2][4];
    #pragma unroll
    for (int i = 0; i < 2; i++)
        #pragma unroll
        for (int j = 0; j < 4; j++)
            acc[i][j] = (f32x4){0.f, 0.f, 0.f, 0.f};

    for (int kb = 0; kb < S_SZ; kb += 64) {
        __syncthreads();
        #pragma unroll
        for (int c = 0; c < 2; c++) {          // A: 8 chunks, 2 per wave
            int ch = wave * 2 + c;
            int row = ch * 8 + lrow8;
            glds16(&hh[(size_t)(m0 + row) * S_SZ + kb + scolh], &As[ch * 512]);
        }
        #pragma unroll
        for (int c = 0; c < 4; c++) {          // B: 16 chunks, 4 per wave
            int ch = wave * 4 + c;
            int row = ch * 8 + lrow8;
            glds16(&Wt[(size_t)(n0 + row) * S_SZ + kb + scolh], &Bs[ch * 512]);
        }
        __syncthreads();
        #pragma unroll
        for (int kk = 0; kk < 64; kk += 32) {
            f16x8 a[2], b[4];
            #pragma unroll
            for (int i = 0; i < 2; i++)
                a[i] = __builtin_bit_cast(f16x8,
                    *(const u32x4*)&As[(wr + i * 16 + lrow) * 64 +
                                       ((kk + quad * 8) ^ swz)]);
            #pragma unroll
            for (int j = 0; j < 4; j++)
                b[j] = __builtin_bit_cast(f16x8,
                    *(const u32x4*)&Bs[(wc + j * 16 + lrow) * 64 +
                                       ((kk + quad * 8) ^ swz)]);
            #pragma unroll
            for (int i = 0; i < 2; i++)
                #pragma unroll
                for (int j = 0; j < 4; j++)
                    acc[i][j] = __builtin_amdgcn_mfma_f32_16x16x32_f16(
                        a[i], b[j], acc[i][j], 0, 0, 0);
        }
    }

    #pragma unroll
    for (int i = 0; i < 2; i++) {
        #pragma unroll
        for (int r = 0; r < 4; r++) {
            int m = m0 + wr + i * 16 + quad * 4 + r;
            float a0 = act[((size_t)m * F_SZ + t) * 2 + 0];
            float a1 = act[((size_t)m * F_SZ + t) * 2 + 1];
            #pragma unroll
            for (int j = 0; j < 4; j++) {
                int n = n0 + wc + j * 16 + lrow;
                parts[(size_t)(m - m_base) * N3 + n] =
                    (f16)(acc[i][j][r] + a0 * Mx[n] + a1 * Mx[N3 + n]);
            }
        }
    }
}

// ---------------------------------------------------------------------------
// LayerNorm + gates + h update. One block per row; thread t owns units t*4..t*4+3.
__global__ __launch_bounds__(256) void ln_gate_step(
    const f16* __restrict__ parts,
    const float* __restrict__ gamma,
    const float* __restrict__ beta,
    float* __restrict__ h,          // fp32 state == d_out[0 .. B*S)
    f16* __restrict__ hh,           // fp16 shadow for next GEMM
    int m_base)
{
    const int rloc = blockIdx.x;
    const int row  = m_base + rloc;
    const int tid  = threadIdx.x;
    const f16* p = parts + (size_t)rloc * N3;
    f16x4 pr = *(const f16x4*)(p + tid * 4);
    f16x4 pc = *(const f16x4*)(p + S_SZ + tid * 4);
    f16x4 pu = *(const f16x4*)(p + 2 * S_SZ + tid * 4);
    float vr[4], vc[4], vu[4];
    float s = 0.f, ss = 0.f;
    #pragma unroll
    for (int q = 0; q < 4; q++) {
        vr[q] = (float)pr[q]; vc[q] = (float)pc[q]; vu[q] = (float)pu[q];
        s  += vr[q] + vc[q] + vu[q];
        ss += vr[q] * vr[q] + vc[q] * vc[q] + vu[q] * vu[q];
    }
    #pragma unroll
    for (int o = 32; o > 0; o >>= 1) {
        s  += __shfl_down(s, o);
        ss += __shfl_down(ss, o);
    }
    __shared__ float red[8];
    int lane = tid & 63, wave = tid >> 6;
    if (lane == 0) { red[wave] = s; red[4 + wave] = ss; }
    __syncthreads();
    float S  = red[0] + red[1] + red[2] + red[3];
    float SS = red[4] + red[5] + red[6] + red[7];
    float mean = S * (1.f / N3);
    float var  = SS * (1.f / N3) - mean * mean;
    float rstd = rsqrtf(var + 1e-3f);

    f32x4 gr = *(const f32x4*)(gamma + tid * 4);
    f32x4 gc = *(const f32x4*)(gamma + S_SZ + tid * 4);
    f32x4 gu = *(const f32x4*)(gamma + 2 * S_SZ + tid * 4);
    f32x4 br = *(const f32x4*)(beta + tid * 4);
    f32x4 bc = *(const f32x4*)(beta + S_SZ + tid * 4);
    f32x4 bu = *(const f32x4*)(beta + 2 * S_SZ + tid * 4);

    size_t hbase = (size_t)row * S_SZ + tid * 4;
    f32x4 hv = *(const f32x4*)(h + hbase);
    f32x4 hn;
    f16x4 hs;
    #pragma unroll
    for (int q = 0; q < 4; q++) {
        float nr = (vr[q] - mean) * rstd * gr[q] + br[q];
        float nc = (vc[q] - mean) * rstd * gc[q] + bc[q];
        float nu = (vu[q] - mean) * rstd * gu[q] + bu[q];
        float r = 1.f / (1.f + __expf(-nr));
        float c = tanhf(r * nc);
        float u = 1.f / (1.f + __expf(-(nu - 1.f)));
        hn[q] = u * c + (1.f - u) * hv[q];
        hs[q] = (f16)hn[q];
    }
    *(f32x4*)(h + hbase) = hn;
    *(f16x4*)(hh + hbase) = hs;
}

// ---------------------------------------------------------------------------
// out[B*S + row*2 + {0,1}] = h_row @ W_dec + b_dec   (fp32)
__global__ __launch_bounds__(256) void final_out(
    const float* __restrict__ h, const float* __restrict__ Wd,
    const float* __restrict__ bd, float* __restrict__ out)
{
    int row = blockIdx.x * 4 + (threadIdx.x >> 6);
    int lane = threadIdx.x & 63;
    const float* hr = h + (size_t)row * S_SZ;
    float s0 = 0.f, s1 = 0.f;
    #pragma unroll
    for (int k = lane; k < S_SZ; k += 64) {
        float x = hr[k];
        s0 += x * Wd[k * 2];
        s1 += x * Wd[k * 2 + 1];
    }
    #pragma unroll
    for (int o = 32; o > 0; o >>= 1) {
        s0 += __shfl_down(s0, o);
        s1 += __shfl_down(s1, o);
    }
    if (lane == 0) {
        out[(size_t)B_SZ * S_SZ + row * 2 + 0] = s0 + bd[0];
        out[(size_t)B_SZ * S_SZ + row * 2 + 1] = s1 + bd[1];
    }
}

// ---------------------------------------------------------------------------
extern "C" void kernel_launch(void* const* d_in, const int* in_sizes, int n_in,
                              void* d_out, int out_size, void* d_ws, size_t ws_size,
                              hipStream_t stream)
{
    const float* act = (const float*)d_in[0]; // [2048][50][2]
    const float* We  = (const float*)d_in[1]; // [2][1024]
    const float* Wg  = (const float*)d_in[2]; // [2048][3072]
    const float* lng = (const float*)d_in[3]; // [3072]
    const float* lnb = (const float*)d_in[4]; // [3072]
    const float* Wd  = (const float*)d_in[5]; // [1024][2]
    const float* bd  = (const float*)d_in[6]; // [2]
    float* out = (float*)d_out;               // fp32 [B*S h_last][B*2 outputs]
    float* h   = out;                         // fp32 h state aliased in d_out

    char* ws = (char*)d_ws;
    f16*   Wt = (f16*)ws;                       // 6,291,456 B
    float* Mx = (float*)(ws + 6291456);         //    24,576 B
    f16*   hh = (f16*)(ws + 6316032);           // 4,194,304 B fp16 shadow state
    const size_t BASE = 6316032 + 4194304;      // 10,510,336
    f16* parts = (f16*)(ws + BASE);
    size_t avail = (ws_size > BASE) ? ws_size - BASE : 0;
    int rows = 2048;
    while (rows > 128 && (size_t)rows * N3 * 2 > avail) rows >>= 1;

    hipMemsetAsync(h, 0, (size_t)B_SZ * S_SZ * 4, stream);
    hipMemsetAsync(hh, 0, (size_t)B_SZ * S_SZ * 2, stream);
    hipMemsetAsync(Mx, 0, 2 * N3 * 4, stream);
    make_mx<<<dim3(N3 / 256, 16), 256, 0, stream>>>(We, Wg, Mx);
    transpose_w<<<dim3(N3 / 32, S_SZ / 32), 256, 0, stream>>>(Wg, Wt);

    for (int t = 0; t < F_SZ; t++) {
        for (int mb = 0; mb < B_SZ; mb += rows) {
            gemm_step<<<dim3(rows / 64, N3 / 128), 256, 0, stream>>>(
                Wt, hh, Mx, act, parts, t, mb);
            ln_gate_step<<<rows, 256, 0, stream>>>(parts, lng, lnb, h, hh, mb);
        }
    }
    final_out<<<B_SZ / 4, 256, 0, stream>>>(h, Wd, bd, out);
}